// Round 13
// baseline (222.243 us; speedup 1.0000x reference)
//
#include <hip/hip_runtime.h>

typedef unsigned short ushort_t;
typedef __attribute__((ext_vector_type(4))) unsigned short bfx4;
typedef __attribute__((ext_vector_type(8))) unsigned short bfx8;
typedef __attribute__((ext_vector_type(8))) short sfx8;
typedef __attribute__((ext_vector_type(4))) float fx4;

#define NABLK  512     // phase-A blocks (512 x 2/CU -> all 256 CUs busy)
#define RTH    1024    // phase-A threads per block
#define KBMAX  52      // max buckets (node>>10); N <= 53248 (node id fits 16 bits) else fallback
#define CAPL   60      // LDS records per bucket: 52*60*6*4=74880B -> total ~77.3KB -> 2 blocks/CU
#define FLC    16      // flush chunk, records
#define RD     6       // record dwords (24 B): 4x f16x2 + (f16|id<<16) + pad
#define QMAX   224     // flush queue capacity per round (<= KBMAX*4)
#define SPN    8       // phase-B sub-blocks per bucket (part table = KB*8*40KB = 16MB)
#define ATB    512     // phase-B threads per block

#define FXS 4194304.0f           // 2^22 fixed-point scale (range ±512, lsb 2.4e-7)
#define FXONE (1 << 22)

__device__ __forceinline__ float bf2f(unsigned short u){
  unsigned int x = ((unsigned int)u) << 16;
  float f; __builtin_memcpy(&f, &x, 4); return f;
}
__device__ __forceinline__ unsigned short f2bf(float f){
  unsigned int x; __builtin_memcpy(&x, &f, 4);
  x += 0x7fffu + ((x >> 16) & 1u);
  return (unsigned short)(x >> 16);
}
__device__ __forceinline__ int f2fx(float v){ return __float2int_rn(v * FXS); }
__device__ __forceinline__ unsigned short f2h(float f){
  _Float16 h = (_Float16)f;
  unsigned short u; __builtin_memcpy(&u, &h, 2); return u;
}
__device__ __forceinline__ float h2f(unsigned int u16){
  unsigned short us = (unsigned short)u16;
  _Float16 h; __builtin_memcpy(&h, &us, 2); return (float)h;
}
__device__ __forceinline__ unsigned int pk2(float a, float b){
  return (unsigned int)f2h(a) | ((unsigned int)f2h(b) << 16);
}

// ---------------- fallback-mode prep: zero sums + pack W_so (binned mode does not use this)
__global__ __launch_bounds__(256) void k_prep(const float* __restrict__ wso,
                                              ushort_t* __restrict__ wpk,
                                              float* __restrict__ sums, int N10)
{
  int gid = blockIdx.x * 256 + threadIdx.x;
  int b4 = gid * 4;
  if (b4 + 4 <= N10){
    fx4 z = {0.f, 0.f, 0.f, 0.f};
    *(fx4*)(sums + b4) = z;
  } else if (b4 < N10){
    for (int t = b4; t < N10; t++) sums[t] = 0.f;
  }
  if (gid < 8*5*64*8){
    int j    = gid & 7;
    int lane = (gid >> 3) & 63;
    int ks   = (gid >> 9) % 5;
    int nt   = gid / 2560;
    int mrow = lane & 15, quad = lane >> 4;
    int o = nt*16 + mrow;
    int k = ks*32 + quad*8 + j;
    float v = (k < 153) ? wso[o*153 + k] : 0.f;
    wpk[gid] = f2bf(v);
  }
}

// ---------------- pure-atomic fallback (ws too small / N too large)
__global__ void k_edge(const int* __restrict__ ei, const float* __restrict__ frames,
                       float* __restrict__ sums, int E)
{
  int e = blockIdx.x * 256 + threadIdx.x;
  if (e >= E) return;
  int row = ei[e];
  const float* fp = frames + (size_t)e * 9;
  float F[9];
  __builtin_memcpy(F, fp, 36);
  float* sp = sums + (size_t)row * 10;
  #pragma unroll
  for (int t = 0; t < 9; t++) atomicAdd(&sp[t], F[t]);
  atomicAdd(&sp[9], 1.0f);
}

// ---------------- Phase A: LDS-staged radix partition into per-(bucket,block) record streams.
// Records 24B f16-packed. Overflow (LDS buf / stream cap) goes to a per-block ovrecs stream
// (capacity OVP >= EPB: each edge creates <=1 record -> hard bound, no fabric atomics, no sums).
// Block 0 additionally packs wpk (runs before k_node by kernel ordering).
__global__ __launch_bounds__(RTH) void k_part(const int* __restrict__ ei,
                                              const float* __restrict__ frames,
                                              unsigned int* __restrict__ recs,
                                              int* __restrict__ counts,
                                              unsigned int* __restrict__ ovrecs,
                                              int* __restrict__ counts2,
                                              const float* __restrict__ wso,
                                              ushort_t* __restrict__ wpk,
                                              int E, int EPB, int KB, int CAPG, int OVP)
{
  __shared__ unsigned int s_buf[KBMAX * CAPL * RD];   // 74880B; total ~77.3KB -> 2 blocks/CU
  __shared__ int s_cnt[KBMAX];
  __shared__ int s_gof[KBMAX];
  __shared__ int s_cap[KBMAX];                        // first-fallback doff (stream cap actually stored)
  __shared__ int s_qb[QMAX];                          // (bucket<<8) | srcStartSlot
  __shared__ int s_qd[QMAX];                          // dst record offset, or (-2-ovoff) = overflow
  __shared__ int s_nq;
  __shared__ int s_ovn;                               // overflow records allocated (bounded by EPB)

  const int tid  = threadIdx.x;
  const int ablk = blockIdx.x;
  const int e0 = ablk * EPB;
  const int e1 = min(e0 + EPB, E);

  if (ablk == 0){
    for (int i = tid; i < 8*5*64*8; i += RTH){
      int j    = i & 7;
      int lane = (i >> 3) & 63;
      int ks   = (i >> 9) % 5;
      int nt   = i / 2560;
      int mrow = lane & 15, quad = lane >> 4;
      int o = nt*16 + mrow;
      int k = ks*32 + quad*8 + j;
      float v = (k < 153) ? wso[o*153 + k] : 0.f;
      wpk[i] = f2bf(v);
    }
  }

  for (int b = tid; b < KB; b += RTH){ s_cnt[b] = 0; s_gof[b] = 0; s_cap[b] = CAPG; }
  if (tid == 0){ s_nq = 0; s_ovn = 0; }
  __syncthreads();

  for (int i0 = e0; i0 < e1; i0 += RTH){
    // ---- classify (coalesced reads of ei + frames), pack record into LDS
    int e = i0 + tid;
    if (e < e1){
      int row = ei[e];
      float F[9];
      __builtin_memcpy(F, frames + (size_t)e * 9, 36);
      int b   = row >> 10;
      int loc = row & 1023;
      int slot = atomicAdd(&s_cnt[b], 1);     // ds_add_rtn_u32 (native int)
      if (slot < CAPL){
        uint2* d2 = (uint2*)(s_buf + (b * CAPL + slot) * RD);
        d2[0] = make_uint2(pk2(F[0], F[1]), pk2(F[2], F[3]));
        d2[1] = make_uint2(pk2(F[4], F[5]), pk2(F[6], F[7]));
        d2[2] = make_uint2((unsigned int)f2h(F[8]) | ((unsigned int)loc << 16), 0u);
      } else {
        // LDS buffer overflow (rare): append full record (global node id) to ovrecs
        int ov = atomicAdd(&s_ovn, 1);
        uint2* d2 = (uint2*)(ovrecs + ((size_t)ablk * OVP + ov) * RD);
        d2[0] = make_uint2(pk2(F[0], F[1]), pk2(F[2], F[3]));
        d2[1] = make_uint2(pk2(F[4], F[5]), pk2(F[6], F[7]));
        d2[2] = make_uint2((unsigned int)f2h(F[8]) | ((unsigned int)row << 16), 0u);
      }
    }
    __syncthreads();
    // ---- flush detect: one thread per bucket queues full 16-record chunks (from the top)
    if (tid < KB){
      int c = min(s_cnt[tid], CAPL);
      int nf = c >> 4;
      int rem = c & (FLC - 1);
      if (nf > 0){
        int off = s_gof[tid];
        s_gof[tid] = off + nf * FLC;
        for (int k = 0; k < nf; k++){
          int q = atomicAdd(&s_nq, 1);
          int doff = off + k * FLC;
          s_qb[q] = (tid << 8) | (rem + k * FLC);
          if (doff + FLC <= CAPG){
            s_qd[q] = doff;
          } else {
            int ovo = atomicAdd(&s_ovn, FLC);        // stream-cap overflow -> ovrecs chunk
            s_qd[q] = -2 - ovo;
            s_cap[tid] = min(s_cap[tid], doff);      // doff monotone -> fallbacks are a suffix
          }
        }
        s_cnt[tid] = rem;
      }
    }
    __syncthreads();
    // ---- cooperative copy: 96 dwords per chunk (384B), fully coalesced
    const int nq = s_nq;
    for (int i = tid; i < nq * (FLC * RD); i += RTH){
      int q = i / (FLC * RD), d = i - q * (FLC * RD);
      int bb = s_qb[q] >> 8, ss = s_qb[q] & 255;
      int doff = s_qd[q];
      unsigned int v = s_buf[(bb * CAPL + ss) * RD + d];
      if (doff >= 0){
        recs[((size_t)(bb * NABLK + ablk) * CAPG + doff) * RD + d] = v;
      } else {
        int ovo = -2 - doff;
        int dd = d - (d / RD) * RD;
        if (dd == 4){
          int loc = v >> 16;
          v = (v & 0xFFFFu) | ((unsigned int)((bb << 10) | loc) << 16);  // loc -> global id
        }
        ovrecs[((size_t)ablk * OVP + ovo) * RD + d] = v;
      }
    }
    __syncthreads();
    if (tid == 0) s_nq = 0;   // next read is after the classify barrier
  }

  // ---- drain leftovers (<16 per bucket), one record per thread
  for (int i = tid; i < KB * FLC; i += RTH){
    int b = i / FLC, rec = i - b * FLC;
    if (rec < s_cnt[b]){
      int off = s_gof[b] + rec;
      const unsigned int* rp = s_buf + (b * CAPL + rec) * RD;
      if (off < s_cap[b]){
        unsigned int* dp = recs + ((size_t)(b * NABLK + ablk) * CAPG + off) * RD;
        dp[0]=rp[0]; dp[1]=rp[1]; dp[2]=rp[2]; dp[3]=rp[3]; dp[4]=rp[4]; dp[5]=rp[5];
      } else {
        int ovo = atomicAdd(&s_ovn, 1);
        unsigned int* dp = ovrecs + ((size_t)ablk * OVP + ovo) * RD;
        dp[0]=rp[0]; dp[1]=rp[1]; dp[2]=rp[2]; dp[3]=rp[3];
        unsigned int v4 = rp[4];
        int loc = v4 >> 16;
        dp[4] = (v4 & 0xFFFFu) | ((unsigned int)((b << 10) | loc) << 16);
        dp[5] = rp[5];
      }
    }
  }
  __syncthreads();
  if (tid < KB)
    counts[tid * NABLK + ablk] = min(s_gof[tid] + s_cnt[tid], s_cap[tid]);
  if (tid == 0)
    counts2[ablk] = min(s_ovn, OVP);
}

// ---------------- Phase B: per (bucket, sp) sub-block, sequential record reads.
// Fixed-point int accumulate via native ds_add_u32; part tables stay INT (exact).
// Also folds in its ablk-slice's overflow records (counts2 ~always 0).
__global__ __launch_bounds__(ATB) void k_accum(const unsigned int* __restrict__ recs,
                                               const int* __restrict__ counts,
                                               const unsigned int* __restrict__ ovrecs,
                                               const int* __restrict__ counts2,
                                               int* __restrict__ part, int CAPG, int OVP)
{
  constexpr int APS2 = NABLK / SPN;     // 64
  __shared__ int s_pref[APS2 + 1];
  __shared__ int s_c2[APS2];
  __shared__ int s_acc[1024 * 11];      // fixed-point Q22; stride 11: gcd(11,32)=1
  const int bucket = blockIdx.x / SPN;
  const int sp     = blockIdx.x - bucket * SPN;
  const int tid    = threadIdx.x;

  if (tid < APS2){
    s_pref[tid + 1] = counts[bucket * NABLK + sp * APS2 + tid];
    s_c2[tid]       = counts2[sp * APS2 + tid];
  }
  if (tid == 0) s_pref[0] = 0;
  for (int i = tid; i < 1024 * 11; i += ATB) s_acc[i] = 0;
  __syncthreads();
  #pragma unroll
  for (int off = 1; off < APS2; off <<= 1){
    int v = 0;
    if (tid < APS2 && tid + 1 > off) v = s_pref[tid + 1 - off];
    __syncthreads();
    if (tid < APS2) s_pref[tid + 1] += v;
    __syncthreads();
  }
  const int total = s_pref[APS2];

  for (int base = 0; base < total; base += ATB * 4){
    int got[4]; size_t ra[4];
    #pragma unroll
    for (int u = 0; u < 4; u++){
      got[u] = 0; ra[u] = 0;
      int idx = base + u * ATB + tid;
      if (idx < total){
        int lo = 0, hi = APS2;
        while (hi - lo > 1){ int mid = (lo + hi) >> 1; if (s_pref[mid] <= idx) lo = mid; else hi = mid; }
        int slot = idx - s_pref[lo];
        int ablk = sp * APS2 + lo;
        ra[u] = ((size_t)(bucket * NABLK + ablk) * CAPG + slot);
        got[u] = 1;
      }
    }
    uint2 a0[4], a1[4], a2[4];
    #pragma unroll
    for (int u = 0; u < 4; u++){
      if (got[u]){
        const unsigned int* rp = recs + ra[u] * RD;   // 24B-aligned sequential
        a0[u] = *(const uint2*)(rp + 0);
        a1[u] = *(const uint2*)(rp + 2);
        a2[u] = *(const uint2*)(rp + 4);
      }
    }
    #pragma unroll
    for (int u = 0; u < 4; u++){
      if (got[u]){
        int loc = a2[u].x >> 16;
        int* ap = s_acc + loc * 11;
        atomicAdd(&ap[0], f2fx(h2f(a0[u].x & 65535u)));   // ds_add_u32: native
        atomicAdd(&ap[1], f2fx(h2f(a0[u].x >> 16)));
        atomicAdd(&ap[2], f2fx(h2f(a0[u].y & 65535u)));
        atomicAdd(&ap[3], f2fx(h2f(a0[u].y >> 16)));
        atomicAdd(&ap[4], f2fx(h2f(a1[u].x & 65535u)));
        atomicAdd(&ap[5], f2fx(h2f(a1[u].x >> 16)));
        atomicAdd(&ap[6], f2fx(h2f(a1[u].y & 65535u)));
        atomicAdd(&ap[7], f2fx(h2f(a1[u].y >> 16)));
        atomicAdd(&ap[8], f2fx(h2f(a2[u].x & 65535u)));
        atomicAdd(&ap[9], FXONE);
      }
    }
  }
  // ---- overflow records from this sp's ablk-slice (counts2 ~always 0; only matching bucket folds)
  for (int a2i = 0; a2i < APS2; ++a2i){
    int c2 = s_c2[a2i];
    if (c2 == 0) continue;
    int ablk = sp * APS2 + a2i;
    for (int i = tid; i < c2; i += ATB){
      const unsigned int* rp = ovrecs + ((size_t)ablk * OVP + i) * RD;
      unsigned int r0 = rp[0], r1 = rp[1], r2 = rp[2], r3 = rp[3], r4 = rp[4];
      int node = r4 >> 16;
      if ((node >> 10) == bucket){
        int loc = node & 1023;
        int* ap = s_acc + loc * 11;
        atomicAdd(&ap[0], f2fx(h2f(r0 & 65535u)));
        atomicAdd(&ap[1], f2fx(h2f(r0 >> 16)));
        atomicAdd(&ap[2], f2fx(h2f(r1 & 65535u)));
        atomicAdd(&ap[3], f2fx(h2f(r1 >> 16)));
        atomicAdd(&ap[4], f2fx(h2f(r2 & 65535u)));
        atomicAdd(&ap[5], f2fx(h2f(r2 >> 16)));
        atomicAdd(&ap[6], f2fx(h2f(r3 & 65535u)));
        atomicAdd(&ap[7], f2fx(h2f(r3 >> 16)));
        atomicAdd(&ap[8], f2fx(h2f(r4 & 65535u)));
        atomicAdd(&ap[9], FXONE);
      }
    }
  }
  __syncthreads();
  int* pb = part + (size_t)(bucket * SPN + sp) * 10240;
  for (int i = tid; i < 10240; i += ATB)
    pb[i] = s_acc[(i / 10) * 11 + (i % 10)];
}

// ---------------- Kernel C: node main pass (vh, vdf, vnorm, Fsum->sh, MFMA s, MFMA gate/vrep)
#define NPB 64
#define MS  168   // padded row stride (elements); 168*2B/4 = 84 ≡ 20 mod 32 -> <=2-way LDS conflicts
#define WGS 136   // sm_wg row stride (shorts): 272B, 16B-aligned, 68 dw ≡ 4 mod 32 -> <=2-way

__global__ __launch_bounds__(256) void k_node(
    const float* __restrict__ scalar, const float* __restrict__ vec,
    const float* __restrict__ sums,   const int* __restrict__ part,
    const float* __restrict__ wdown, const float* __restrict__ wdf,
    const ushort_t* __restrict__ wpk, const float* __restrict__ bso,
    const float* __restrict__ wup,   const float* __restrict__ wg,
    const float* __restrict__ bg,
    float* __restrict__ out0, float* __restrict__ out1, int N)
{
  __shared__ __align__(16) ushort_t sm_merged[NPB * MS];  // phases 0-1: first 12288B hold vec f32
  __shared__ __align__(16) ushort_t sm_vh[NPB * 48];
  __shared__ __align__(16) ushort_t sm_wg[16 * WGS];
  __shared__ __align__(16) ushort_t sm_wupb[512];  // [0:256) bf16 hi, [256:512) bf16 lo residual
  __shared__ float  sm_sh[NPB * 10];     // Fsum[9] + cnt per node
  __shared__ float  sm_vdf[NPB * 9];     // vdf[d*3+c] per node
  __shared__ float  sm_wd[256];          // transposed: sm_wd[k*16+h] = wdown[h*16+k]
  __shared__ float  sm_wdf[48];
  __shared__ float  sm_bso[128];
  __shared__ float  sm_bg[16];

  const int tid = threadIdx.x;
  const int n0  = blockIdx.x * NPB;

  // ---- T14 issue-early: scalar loads issued NOW, consumed in phase 2.
  fx4 pf[8];
  #pragma unroll
  for (int it = 0; it < 8; it++){
    int idx = tid + it*256;
    int ni = idx >> 5, c4 = (idx & 31) * 4;
    int g = n0 + ni;
    fx4 z = {0.f, 0.f, 0.f, 0.f};
    pf[it] = (g < N) ? *(const fx4*)(scalar + (size_t)g*128 + c4) : z;
  }

  // ---- phase 0: stage vec (as f32 into sm_merged), wd/wdf, reduce partial Fsum tables (int, exact)
  {
    int nv = N - n0; if (nv > NPB) nv = NPB;
    const int valid = nv * 48;
    fx4* scratch = (fx4*)sm_merged;
    for (int idx = tid; idx < NPB*48/4; idx += 256){
      fx4 val = {0.f, 0.f, 0.f, 0.f};
      if (idx*4 < valid) val = *(const fx4*)(vec + (size_t)n0*48 + idx*4);
      scratch[idx] = val;
    }
  }
  sm_wd[tid] = wdown[(tid & 15)*16 + (tid >> 4)];   // transpose on load
  if (tid < 48) sm_wdf[tid] = wdf[tid];
  for (int idx = tid; idx < NPB*10; idx += 256){
    int ni = idx / 10, sl = idx - ni*10;
    int g = n0 + ni;
    float acc = 0.f;
    if (g < N){
      if (sums) acc = sums[(size_t)g*10 + sl];       // fallback mode only
      if (part){
        int bucket = g >> 10, loc = g & 1023;
        const int* pb = part + (size_t)bucket * SPN * 10240 + loc * 10 + sl;
        int ai = 0;
        #pragma unroll
        for (int sp = 0; sp < SPN; sp++) ai += pb[(size_t)sp * 10240];
        acc += (float)ai * (1.0f / FXS);
      }
    }
    sm_sh[idx] = acc;
  }
  __syncthreads();

  // ---- phase 1: vh (1024 items (ni,h), weight reads broadcast) + vdf (192 items)
  #pragma unroll
  for (int it = 0; it < 4; it++){
    int idx = tid + it*256;
    int ni = idx >> 4, h = idx & 15;
    const float* sv = (const float*)sm_merged + ni*48;
    float a0 = 0.f, a1 = 0.f, a2 = 0.f;
    #pragma unroll
    for (int k = 0; k < 16; k++){
      float w = sm_wd[k*16 + h];
      a0 += sv[k*3+0]*w; a1 += sv[k*3+1]*w; a2 += sv[k*3+2]*w;
    }
    sm_vh[ni*48 +  0 + h] = f2bf(a0);
    sm_vh[ni*48 + 16 + h] = f2bf(a1);
    sm_vh[ni*48 + 32 + h] = f2bf(a2);
  }
  if (tid < NPB*3){
    const int ni = tid / 3, d = tid - ni*3;
    const float* sv = (const float*)sm_merged + ni*48;
    float c0 = 0.f, c1 = 0.f, c2 = 0.f;
    #pragma unroll
    for (int k = 0; k < 16; k++){
      float v = sv[k*3 + d];
      c0 += v * sm_wdf[ 0 + k];
      c1 += v * sm_wdf[16 + k];
      c2 += v * sm_wdf[32 + k];
    }
    sm_vdf[ni*9 + d*3 + 0] = c0;
    sm_vdf[ni*9 + d*3 + 1] = c1;
    sm_vdf[ni*9 + d*3 + 2] = c2;
  }
  __syncthreads();

  // ---- phase 2: assemble merged row (scalar | vnorm | sh | pad), stage small tensors
  #pragma unroll
  for (int it = 0; it < 8; it++){
    int idx = tid + it*256;
    int ni = idx >> 5, c4 = (idx & 31) * 4;
    fx4 x = pf[it];
    bfx4 b; b[0]=f2bf(x[0]); b[1]=f2bf(x[1]); b[2]=f2bf(x[2]); b[3]=f2bf(x[3]);
    *(bfx4*)(sm_merged + ni*MS + c4) = b;
  }
  #pragma unroll
  for (int it = 0; it < 4; it++){
    int idx = tid + it*256;
    int ni = idx >> 4, h = idx & 15;
    float x0 = bf2f(sm_vh[ni*48 +  0 + h]);
    float x1 = bf2f(sm_vh[ni*48 + 16 + h]);
    float x2 = bf2f(sm_vh[ni*48 + 32 + h]);
    sm_merged[ni*MS + 128 + h] = f2bf(sqrtf(x0*x0 + x1*x1 + x2*x2 + 1e-8f));
  }
  // sh[c*3+i] = (Fsum[i][:] . vdf[:][c]) / max(cnt,1)   (factorized rotation, per node)
  for (int idx = tid; idx < NPB*9; idx += 256){
    int ni = idx / 9, t = idx - ni*9;
    int c = t / 3, i3 = (t - c*3) * 3;
    float cnt = sm_sh[ni*10 + 9];
    float inv = 1.0f / fmaxf(cnt, 1.0f);
    const float* Fs = sm_sh + ni*10;
    const float* vd = sm_vdf + ni*9;
    float val = Fs[i3+0]*vd[0*3+c] + Fs[i3+1]*vd[1*3+c] + Fs[i3+2]*vd[2*3+c];
    sm_merged[ni*MS + 144 + t] = f2bf(val * inv);
  }
  for (int idx = tid; idx < NPB*7; idx += 256){
    int ni = idx / 7, t = idx - ni*7;
    sm_merged[ni*MS + 153 + t] = 0;            // zero MFMA pad cols 153..159
  }
  for (int idx = tid; idx < 2048; idx += 256)
    sm_wg[(idx >> 7)*WGS + (idx & 127)] = f2bf(wg[idx]);
  {
    float w = wup[tid];
    unsigned short hi = f2bf(w);
    sm_wupb[tid]       = hi;
    sm_wupb[256 + tid] = f2bf(w - bf2f(hi));
  }
  if (tid < 128) sm_bso[tid] = bso[tid];
  if (tid < 16) sm_bg[tid] = bg[tid];
  __syncthreads();

  // ---- phase 3: MFMA scalar_out (B-fragments streamed from prepacked global, L2-resident)
  const int lane = tid & 63;
  const int wv   = tid >> 6;
  const int mrow = lane & 15;
  const int quad = lane >> 4;
  sfx8 afr[5];
  {
    const ushort_t* ab = sm_merged + (wv*16 + mrow)*MS + quad*8;
    #pragma unroll
    for (int ks = 0; ks < 5; ks++) afr[ks] = *(const sfx8*)(ab + ks*32);
  }
  const ushort_t* wb = wpk + lane*8;
  #pragma unroll
  for (int nt = 0; nt < 8; nt++){
    fx4 acc = {0.f, 0.f, 0.f, 0.f};
    #pragma unroll
    for (int ks = 0; ks < 5; ks++){
      sfx8 bfr = *(const sfx8*)(wb + (size_t)(nt*5 + ks)*64*8);
      acc = __builtin_amdgcn_mfma_f32_16x16x32_bf16(afr[ks], bfr, acc, 0, 0, 0);
    }
    const int o = nt*16 + mrow;
    const float bso_v = sm_bso[o];
    #pragma unroll
    for (int r = 0; r < 4; r++){
      int m = quad*4 + r;
      int g = n0 + wv*16 + m;
      float s = acc[r] + bso_v;
      float sact = s / (1.f + __expf(-s));
      if (g < N) out0[(size_t)g*128 + o] = sact;
      sm_merged[(wv*16 + m)*MS + o] = f2bf(sact);
    }
  }
  __syncthreads();

  // ---- phase 4 (MFMA): gate = sigmoid(silu(s) @ Wg^T + bg); vrep[d] = (vh_d @ Wup^T) * gate
  {
    fx4 accg = {0.f, 0.f, 0.f, 0.f};
    const ushort_t* ga = sm_merged + (wv*16 + mrow)*MS + quad*8;
    const ushort_t* gb = sm_wg + mrow*WGS + quad*8;
    #pragma unroll
    for (int ks = 0; ks < 4; ks++){
      sfx8 af = *(const sfx8*)(ga + ks*32);
      sfx8 bf = *(const sfx8*)(gb + ks*32);
      accg = __builtin_amdgcn_mfma_f32_16x16x32_bf16(af, bf, accg, 0, 0, 0);
    }
    float sig[4];
    #pragma unroll
    for (int r = 0; r < 4; r++){
      float gv = accg[r] + sm_bg[mrow];
      sig[r] = 1.f / (1.f + __expf(-gv));
    }
    const sfx8 zero8 = {0,0,0,0,0,0,0,0};
    sfx8 bhi = zero8, blo = zero8;
    if (quad < 2){
      bhi = *(const sfx8*)(sm_wupb + mrow*16 + quad*8);
      blo = *(const sfx8*)(sm_wupb + 256 + mrow*16 + quad*8);
    }
    #pragma unroll
    for (int d = 0; d < 3; d++){
      sfx8 av = zero8;
      if (quad < 2)
        av = *(const sfx8*)(sm_vh + (wv*16 + mrow)*48 + d*16 + quad*8);
      fx4 accv = {0.f, 0.f, 0.f, 0.f};
      accv = __builtin_amdgcn_mfma_f32_16x16x32_bf16(av, blo, accv, 0, 0, 0);
      accv = __builtin_amdgcn_mfma_f32_16x16x32_bf16(av, bhi, accv, 0, 0, 0);
      #pragma unroll
      for (int r = 0; r < 4; r++){
        int m = quad*4 + r;
        int g = n0 + wv*16 + m;
        if (g < N) out1[((size_t)g*16 + mrow)*3 + d] = accv[r] * sig[r];
      }
    }
  }
}

extern "C" void kernel_launch(void* const* d_in, const int* in_sizes, int n_in,
                              void* d_out, int out_size, void* d_ws, size_t ws_size,
                              hipStream_t stream)
{
  const float* scalar = (const float*)d_in[0];
  const float* vec    = (const float*)d_in[1];
  const int*   ei     = (const int*)d_in[2];
  const float* frames = (const float*)d_in[3];
  const float* wdown  = (const float*)d_in[4];
  const float* wdf    = (const float*)d_in[5];
  const float* wso    = (const float*)d_in[6];
  const float* bso    = (const float*)d_in[7];
  const float* wup    = (const float*)d_in[8];
  const float* wg     = (const float*)d_in[9];
  const float* bg     = (const float*)d_in[10];

  const int N = in_sizes[0] / 128;
  const int E = in_sizes[2] / 2;
  const int KB  = (N + 1023) >> 10;                // buckets of 1024 nodes
  const int EPB = (E + NABLK - 1) / NABLK;         // edges per phase-A block

  // per-(bucket,ablock) stream capacity: mean + 3.5 sigma + slack, 16-aligned
  float lam = (float)EPB / (float)KB;
  int capg = (int)(lam + 3.5f * sqrtf(lam) + 17.0f);
  capg = (capg + 15) & ~15;
  const int OVP = (EPB + FLC - 1) & ~(FLC - 1);    // hard overflow bound: <=1 record/edge

  // binned layout: no pre-zeroing needed anywhere (all streams counter-bounded; part overwritten)
  char* wp = (char*)d_ws;
  ushort_t*     wpk    = (ushort_t*)wp;            wp += (size_t)8*5*64*8 * sizeof(ushort_t);
  int*          counts = (int*)wp;                 wp += (size_t)KB * NABLK * sizeof(int);
  int*          counts2= (int*)wp;                 wp += (size_t)NABLK * sizeof(int);
  unsigned int* recs   = (unsigned int*)wp;        wp += (size_t)KB * NABLK * capg * RD * sizeof(unsigned int);
  unsigned int* ovrecs = (unsigned int*)wp;        wp += (size_t)NABLK * OVP * RD * sizeof(unsigned int);
  int*          part   = (int*)wp;                 wp += (size_t)KB * SPN * 10240 * sizeof(int);
  const size_t ws_needed = (size_t)(wp - (char*)d_ws);

  float* out0 = (float*)d_out;                     // silu(s): N x 128 f32
  float* out1 = out0 + (size_t)N * 128;            // vrep:    N x 16 x 3 f32

  const bool binned = (ws_size >= ws_needed) && (KB <= KBMAX) && (E < (1 << 25));

  if (binned){
    k_part<<<NABLK, RTH, 0, stream>>>(ei, frames, recs, counts, ovrecs, counts2,
                                      wso, wpk, E, EPB, KB, capg, OVP);
    k_accum<<<KB * SPN, ATB, 0, stream>>>(recs, counts, ovrecs, counts2, part, capg, OVP);
    k_node<<<(N + NPB - 1) / NPB, 256, 0, stream>>>(scalar, vec, nullptr, part,
                                                    wdown, wdf, wpk, bso, wup, wg, bg,
                                                    out0, out1, N);
  } else {
    // fallback: sums + wpk at workspace base
    char* fp_ = (char*)d_ws;
    float*    sums  = (float*)fp_;                 fp_ += (size_t)N * 10 * sizeof(float);
    ushort_t* wpk2  = (ushort_t*)fp_;
    const int N10 = N * 10;
    int prepBlocks = ((N10 + 3) / 4 + 255) / 256;
    if (prepBlocks < 80) prepBlocks = 80;
    k_prep<<<prepBlocks, 256, 0, stream>>>(wso, wpk2, sums, N10);
    k_edge<<<(E + 255) / 256, 256, 0, stream>>>(ei, frames, sums, E);
    k_node<<<(N + NPB - 1) / NPB, 256, 0, stream>>>(scalar, vec, sums, nullptr,
                                                    wdown, wdf, wpk2, bso, wup, wg, bg,
                                                    out0, out1, N);
  }
}

// Round 14
// 212.469 us; speedup vs baseline: 1.0460x; 1.0460x over previous
//
#include <hip/hip_runtime.h>

typedef unsigned short ushort_t;
typedef __attribute__((ext_vector_type(4))) unsigned short bfx4;
typedef __attribute__((ext_vector_type(8))) unsigned short bfx8;
typedef __attribute__((ext_vector_type(8))) short sfx8;
typedef __attribute__((ext_vector_type(4))) float fx4;

#define NABLK  512     // phase-A blocks (512 x 2/CU -> all 256 CUs busy)
#define RTH    1024    // phase-A threads per block
#define KBMAX  52      // max buckets (node>>10); N <= 53248 else fallback
#define CAPL   60      // LDS records per bucket: 52*60*6*4=74880B -> total ~77.3KB -> 2 blocks/CU
#define FLC    16      // flush chunk, records
#define RD     6       // record dwords (24 B): 4x f16x2 + (f16|loc<<16) + pad
#define QMAX   224     // flush queue capacity per round (<= KBMAX*4)
#define SPN    8       // phase-B sub-blocks per bucket (part table = KB*8*40KB = 16MB)
#define ATB    512     // phase-B threads per block

#define FXS 4194304.0f           // 2^22 fixed-point scale (range ±512, lsb 2.4e-7)
#define FXONE (1 << 22)

__device__ __forceinline__ float bf2f(unsigned short u){
  unsigned int x = ((unsigned int)u) << 16;
  float f; __builtin_memcpy(&f, &x, 4); return f;
}
__device__ __forceinline__ unsigned short f2bf(float f){
  unsigned int x; __builtin_memcpy(&x, &f, 4);
  x += 0x7fffu + ((x >> 16) & 1u);
  return (unsigned short)(x >> 16);
}
__device__ __forceinline__ int f2fx(float v){ return __float2int_rn(v * FXS); }
__device__ __forceinline__ unsigned short f2h(float f){
  _Float16 h = (_Float16)f;
  unsigned short u; __builtin_memcpy(&u, &h, 2); return u;
}
__device__ __forceinline__ float h2f(unsigned int u16){
  unsigned short us = (unsigned short)u16;
  _Float16 h; __builtin_memcpy(&h, &us, 2); return (float)h;
}
__device__ __forceinline__ unsigned int pk2(float a, float b){
  return (unsigned int)f2h(a) | ((unsigned int)f2h(b) << 16);
}

// ---------------- prep: zero sums (fx4 stores) + pack W_so into bf16 MFMA-B-fragment order.
__global__ __launch_bounds__(256) void k_prep(const float* __restrict__ wso,
                                              ushort_t* __restrict__ wpk,
                                              float* __restrict__ sums, int N10)
{
  int gid = blockIdx.x * 256 + threadIdx.x;
  int b4 = gid * 4;
  if (b4 + 4 <= N10){
    fx4 z = {0.f, 0.f, 0.f, 0.f};
    *(fx4*)(sums + b4) = z;
  } else if (b4 < N10){
    for (int t = b4; t < N10; t++) sums[t] = 0.f;
  }
  if (gid < 8*5*64*8){
    int j    = gid & 7;
    int lane = (gid >> 3) & 63;
    int ks   = (gid >> 9) % 5;
    int nt   = gid / 2560;
    int mrow = lane & 15, quad = lane >> 4;
    int o = nt*16 + mrow;
    int k = ks*32 + quad*8 + j;
    float v = (k < 153) ? wso[o*153 + k] : 0.f;
    wpk[gid] = f2bf(v);
  }
}

// ---------------- pure-atomic fallback (ws too small / N too large)
__global__ void k_edge(const int* __restrict__ ei, const float* __restrict__ frames,
                       float* __restrict__ sums, int E)
{
  int e = blockIdx.x * 256 + threadIdx.x;
  if (e >= E) return;
  int row = ei[e];
  const float* fp = frames + (size_t)e * 9;
  float F[9];
  __builtin_memcpy(F, fp, 36);
  float* sp = sums + (size_t)row * 10;
  #pragma unroll
  for (int t = 0; t < 9; t++) atomicAdd(&sp[t], F[t]);
  atomicAdd(&sp[9], 1.0f);
}

// ---------------- Phase A: LDS-staged radix partition into per-(bucket,block) record streams.
// Records are 24B f16-packed (loc + 9 frame values). All stream writes full-line coalesced.
// Software-pipelined: round r+1's (ei,frames) loads issue during round r's flush/copy phases.
// __launch_bounds__(RTH,8) pins VGPR <= 64 so 2 blocks/CU (16+16 waves) is preserved.
__global__ __launch_bounds__(RTH, 8) void k_part(const int* __restrict__ ei,
                                                 const float* __restrict__ frames,
                                                 unsigned int* __restrict__ recs,
                                                 int* __restrict__ counts,
                                                 float* __restrict__ sums,
                                                 int E, int EPB, int KB, int CAPG)
{
  __shared__ unsigned int s_buf[KBMAX * CAPL * RD];   // 74880B; total ~77.3KB -> 2 blocks/CU
  __shared__ int s_cnt[KBMAX];
  __shared__ int s_gof[KBMAX];
  __shared__ int s_cap[KBMAX];                        // first-fallback doff (stream cap actually stored)
  __shared__ int s_qb[QMAX];                          // (bucket<<8) | srcStartSlot
  __shared__ int s_qd[QMAX];                          // dst record offset, or -1 = fallback
  __shared__ int s_nq;

  const int tid  = threadIdx.x;
  const int ablk = blockIdx.x;
  const int e0 = ablk * EPB;
  const int e1 = min(e0 + EPB, E);

  for (int b = tid; b < KB; b += RTH){ s_cnt[b] = 0; s_gof[b] = 0; s_cap[b] = CAPG; }
  if (tid == 0) s_nq = 0;
  __syncthreads();

  // preload round 0
  int   rowC = -1;
  float FC[9];
  {
    int e = e0 + tid;
    if (e < e1){
      rowC = ei[e];
      __builtin_memcpy(FC, frames + (size_t)e * 9, 36);
    }
  }

  for (int i0 = e0; i0 < e1; i0 += RTH){
    // ---- issue next round's loads (latency hides under this round's LDS phases)
    int   rowN = -1;
    float FN[9];
    if (i0 + RTH < e1){
      int en = i0 + RTH + tid;
      if (en < e1){
        rowN = ei[en];
        __builtin_memcpy(FN, frames + (size_t)en * 9, 36);
      }
    }
    // ---- classify current (preloaded), pack record into LDS
    if (rowC >= 0){
      int b   = rowC >> 10;
      int loc = rowC & 1023;
      int slot = atomicAdd(&s_cnt[b], 1);     // ds_add_rtn_u32 (native int)
      if (slot < CAPL){
        uint2* d2 = (uint2*)(s_buf + (b * CAPL + slot) * RD);
        d2[0] = make_uint2(pk2(FC[0], FC[1]), pk2(FC[2], FC[3]));
        d2[1] = make_uint2(pk2(FC[4], FC[5]), pk2(FC[6], FC[7]));
        d2[2] = make_uint2((unsigned int)f2h(FC[8]) | ((unsigned int)loc << 16), 0u);
      } else {
        // LDS buffer overflow (rare): fabric atomics, correctness-preserving
        float* sp = sums + (size_t)rowC * 10;
        #pragma unroll
        for (int t = 0; t < 9; t++) atomicAdd(&sp[t], FC[t]);
        atomicAdd(&sp[9], 1.0f);
      }
    }
    __syncthreads();
    // ---- flush detect: one thread per bucket queues full 16-record chunks (from the top)
    if (tid < KB){
      int c = min(s_cnt[tid], CAPL);
      int nf = c >> 4;
      int rem = c & (FLC - 1);
      if (nf > 0){
        int off = s_gof[tid];
        s_gof[tid] = off + nf * FLC;
        for (int k = 0; k < nf; k++){
          int q = atomicAdd(&s_nq, 1);
          int doff = off + k * FLC;
          s_qb[q] = (tid << 8) | (rem + k * FLC);
          if (doff + FLC <= CAPG){
            s_qd[q] = doff;
          } else {
            s_qd[q] = -1;
            s_cap[tid] = min(s_cap[tid], doff);   // doff monotone -> fallbacks are a suffix
          }
        }
        s_cnt[tid] = rem;
      }
    }
    __syncthreads();
    // ---- cooperative copy: 96 dwords per chunk (384B), fully coalesced
    const int nq = s_nq;
    for (int i = tid; i < nq * (FLC * RD); i += RTH){
      int q = i / (FLC * RD), d = i - q * (FLC * RD);
      int doff = s_qd[q];
      if (doff >= 0){
        int bb = s_qb[q] >> 8, ss = s_qb[q] & 255;
        recs[((size_t)(bb * NABLK + ablk) * CAPG + doff) * RD + d] =
            s_buf[(bb * CAPL + ss) * RD + d];
      }
    }
    // ---- fallback pass for capacity-overflowed chunks (rare): per-record fabric atomics
    for (int i = tid; i < nq * FLC; i += RTH){
      int q = i / FLC, rr = i - q * FLC;
      if (s_qd[q] < 0){
        int bb = s_qb[q] >> 8, ss = (s_qb[q] & 255) + rr;
        const unsigned int* rp = s_buf + (bb * CAPL + ss) * RD;
        int loc = rp[4] >> 16;
        float* sp = sums + (size_t)((bb << 10) + loc) * 10;
        atomicAdd(&sp[0], h2f(rp[0] & 65535u)); atomicAdd(&sp[1], h2f(rp[0] >> 16));
        atomicAdd(&sp[2], h2f(rp[1] & 65535u)); atomicAdd(&sp[3], h2f(rp[1] >> 16));
        atomicAdd(&sp[4], h2f(rp[2] & 65535u)); atomicAdd(&sp[5], h2f(rp[2] >> 16));
        atomicAdd(&sp[6], h2f(rp[3] & 65535u)); atomicAdd(&sp[7], h2f(rp[3] >> 16));
        atomicAdd(&sp[8], h2f(rp[4] & 65535u)); atomicAdd(&sp[9], 1.0f);
      }
    }
    __syncthreads();
    if (tid == 0) s_nq = 0;   // next read is after the classify barrier
    // ---- rotate prefetched registers
    rowC = rowN;
    #pragma unroll
    for (int t = 0; t < 9; t++) FC[t] = FN[t];
  }

  // ---- drain leftovers (<16 per bucket) + write counts
  for (int i = tid; i < KB * FLC; i += RTH){
    int b = i / FLC, rec = i - b * FLC;
    if (rec < s_cnt[b]){
      int off = s_gof[b] + rec;
      const unsigned int* rp = s_buf + (b * CAPL + rec) * RD;
      if (off < s_cap[b]){
        uint2* dp = (uint2*)(recs + ((size_t)(b * NABLK + ablk) * CAPG + off) * RD);
        dp[0] = make_uint2(rp[0], rp[1]);
        dp[1] = make_uint2(rp[2], rp[3]);
        dp[2] = make_uint2(rp[4], rp[5]);
      } else {
        int loc = rp[4] >> 16;
        float* sp = sums + (size_t)((b << 10) + loc) * 10;
        atomicAdd(&sp[0], h2f(rp[0] & 65535u)); atomicAdd(&sp[1], h2f(rp[0] >> 16));
        atomicAdd(&sp[2], h2f(rp[1] & 65535u)); atomicAdd(&sp[3], h2f(rp[1] >> 16));
        atomicAdd(&sp[4], h2f(rp[2] & 65535u)); atomicAdd(&sp[5], h2f(rp[2] >> 16));
        atomicAdd(&sp[6], h2f(rp[3] & 65535u)); atomicAdd(&sp[7], h2f(rp[3] >> 16));
        atomicAdd(&sp[8], h2f(rp[4] & 65535u)); atomicAdd(&sp[9], 1.0f);
      }
    }
  }
  if (tid < KB)
    counts[tid * NABLK + ablk] = min(s_gof[tid] + s_cnt[tid], s_cap[tid]);
}

// ---------------- Phase B: per (bucket, sp) sub-block, sequential record reads.
// Fixed-point int accumulate via native ds_add_u32; partial tables stay INT (exact, no cvt).
// 512 threads x (KB*8) blocks: same thread-parallelism as 256x(KB*16), half the part traffic.
__global__ __launch_bounds__(ATB) void k_accum(const unsigned int* __restrict__ recs,
                                               const int* __restrict__ counts,
                                               int* __restrict__ part, int CAPG)
{
  constexpr int APS2 = NABLK / SPN;     // 64
  __shared__ int s_pref[APS2 + 1];
  __shared__ int s_acc[1024 * 11];      // fixed-point Q22; stride 11: gcd(11,32)=1
  const int bucket = blockIdx.x / SPN;
  const int sp     = blockIdx.x - bucket * SPN;
  const int tid    = threadIdx.x;

  if (tid < APS2) s_pref[tid + 1] = counts[bucket * NABLK + sp * APS2 + tid];
  if (tid == 0) s_pref[0] = 0;
  for (int i = tid; i < 1024 * 11; i += ATB) s_acc[i] = 0;
  __syncthreads();
  #pragma unroll
  for (int off = 1; off < APS2; off <<= 1){
    int v = 0;
    if (tid < APS2 && tid + 1 > off) v = s_pref[tid + 1 - off];
    __syncthreads();
    if (tid < APS2) s_pref[tid + 1] += v;
    __syncthreads();
  }
  const int total = s_pref[APS2];

  for (int base = 0; base < total; base += ATB * 4){
    int got[4]; size_t ra[4];
    #pragma unroll
    for (int u = 0; u < 4; u++){
      got[u] = 0; ra[u] = 0;
      int idx = base + u * ATB + tid;
      if (idx < total){
        int lo = 0, hi = APS2;
        while (hi - lo > 1){ int mid = (lo + hi) >> 1; if (s_pref[mid] <= idx) lo = mid; else hi = mid; }
        int slot = idx - s_pref[lo];
        int ablk = sp * APS2 + lo;
        ra[u] = ((size_t)(bucket * NABLK + ablk) * CAPG + slot);
        got[u] = 1;
      }
    }
    uint2 a0[4], a1[4], a2[4];
    #pragma unroll
    for (int u = 0; u < 4; u++){
      if (got[u]){
        const unsigned int* rp = recs + ra[u] * RD;   // 24B-aligned sequential
        a0[u] = *(const uint2*)(rp + 0);
        a1[u] = *(const uint2*)(rp + 2);
        a2[u] = *(const uint2*)(rp + 4);
      }
    }
    #pragma unroll
    for (int u = 0; u < 4; u++){
      if (got[u]){
        int loc = a2[u].x >> 16;
        int* ap = s_acc + loc * 11;
        atomicAdd(&ap[0], f2fx(h2f(a0[u].x & 65535u)));   // ds_add_u32: native
        atomicAdd(&ap[1], f2fx(h2f(a0[u].x >> 16)));
        atomicAdd(&ap[2], f2fx(h2f(a0[u].y & 65535u)));
        atomicAdd(&ap[3], f2fx(h2f(a0[u].y >> 16)));
        atomicAdd(&ap[4], f2fx(h2f(a1[u].x & 65535u)));
        atomicAdd(&ap[5], f2fx(h2f(a1[u].x >> 16)));
        atomicAdd(&ap[6], f2fx(h2f(a1[u].y & 65535u)));
        atomicAdd(&ap[7], f2fx(h2f(a1[u].y >> 16)));
        atomicAdd(&ap[8], f2fx(h2f(a2[u].x & 65535u)));
        atomicAdd(&ap[9], FXONE);
      }
    }
  }
  __syncthreads();
  int* pb = part + (size_t)(bucket * SPN + sp) * 10240;
  for (int i = tid; i < 10240; i += ATB)
    pb[i] = s_acc[(i / 10) * 11 + (i % 10)];
}

// ---------------- Kernel C: node main pass (vh, vdf, vnorm, Fsum->sh, MFMA s, MFMA gate/vrep)
#define NPB 64
#define MS  168   // padded row stride (elements); 168*2B/4 = 84 ≡ 20 mod 32 -> <=2-way LDS conflicts
#define WGS 136   // sm_wg row stride (shorts): 272B, 16B-aligned, 68 dw ≡ 4 mod 32 -> <=2-way

__global__ __launch_bounds__(256) void k_node(
    const float* __restrict__ scalar, const float* __restrict__ vec,
    const float* __restrict__ sums,   const int* __restrict__ part,
    const float* __restrict__ wdown, const float* __restrict__ wdf,
    const ushort_t* __restrict__ wpk, const float* __restrict__ bso,
    const float* __restrict__ wup,   const float* __restrict__ wg,
    const float* __restrict__ bg,
    float* __restrict__ out0, float* __restrict__ out1, int N)
{
  __shared__ __align__(16) ushort_t sm_merged[NPB * MS];  // phases 0-1: first 12288B hold vec f32
  __shared__ __align__(16) ushort_t sm_vh[NPB * 48];
  __shared__ __align__(16) ushort_t sm_wg[16 * WGS];
  __shared__ __align__(16) ushort_t sm_wupb[512];  // [0:256) bf16 hi, [256:512) bf16 lo residual
  __shared__ float  sm_sh[NPB * 10];     // Fsum[9] + cnt per node
  __shared__ float  sm_vdf[NPB * 9];     // vdf[d*3+c] per node
  __shared__ float  sm_wd[256];          // transposed: sm_wd[k*16+h] = wdown[h*16+k]
  __shared__ float  sm_wdf[48];
  __shared__ float  sm_bso[128];
  __shared__ float  sm_bg[16];

  const int tid = threadIdx.x;
  const int n0  = blockIdx.x * NPB;

  // ---- T14 issue-early: scalar loads issued NOW, consumed in phase 2.
  fx4 pf[8];
  #pragma unroll
  for (int it = 0; it < 8; it++){
    int idx = tid + it*256;
    int ni = idx >> 5, c4 = (idx & 31) * 4;
    int g = n0 + ni;
    fx4 z = {0.f, 0.f, 0.f, 0.f};
    pf[it] = (g < N) ? *(const fx4*)(scalar + (size_t)g*128 + c4) : z;
  }

  // ---- phase 0: stage vec (as f32 into sm_merged), wd/wdf, reduce partial Fsum tables (int, exact)
  {
    int nv = N - n0; if (nv > NPB) nv = NPB;
    const int valid = nv * 48;
    fx4* scratch = (fx4*)sm_merged;
    for (int idx = tid; idx < NPB*48/4; idx += 256){
      fx4 val = {0.f, 0.f, 0.f, 0.f};
      if (idx*4 < valid) val = *(const fx4*)(vec + (size_t)n0*48 + idx*4);
      scratch[idx] = val;
    }
  }
  sm_wd[tid] = wdown[(tid & 15)*16 + (tid >> 4)];   // transpose on load
  if (tid < 48) sm_wdf[tid] = wdf[tid];
  for (int idx = tid; idx < NPB*10; idx += 256){
    int ni = idx / 10, sl = idx - ni*10;
    int g = n0 + ni;
    float acc = 0.f;
    if (g < N){
      acc = sums[(size_t)g*10 + sl];           // rare overflow-fallback adds (usually 0)
      if (part){
        int bucket = g >> 10, loc = g & 1023;
        const int* pb = part + (size_t)bucket * SPN * 10240 + loc * 10 + sl;
        int ai = 0;
        #pragma unroll
        for (int sp = 0; sp < SPN; sp++) ai += pb[(size_t)sp * 10240];
        acc += (float)ai * (1.0f / FXS);
      }
    }
    sm_sh[idx] = acc;
  }
  __syncthreads();

  // ---- phase 1: vh (1024 items (ni,h), weight reads broadcast) + vdf (192 items)
  #pragma unroll
  for (int it = 0; it < 4; it++){
    int idx = tid + it*256;
    int ni = idx >> 4, h = idx & 15;
    const float* sv = (const float*)sm_merged + ni*48;
    float a0 = 0.f, a1 = 0.f, a2 = 0.f;
    #pragma unroll
    for (int k = 0; k < 16; k++){
      float w = sm_wd[k*16 + h];
      a0 += sv[k*3+0]*w; a1 += sv[k*3+1]*w; a2 += sv[k*3+2]*w;
    }
    sm_vh[ni*48 +  0 + h] = f2bf(a0);
    sm_vh[ni*48 + 16 + h] = f2bf(a1);
    sm_vh[ni*48 + 32 + h] = f2bf(a2);
  }
  if (tid < NPB*3){
    const int ni = tid / 3, d = tid - ni*3;
    const float* sv = (const float*)sm_merged + ni*48;
    float c0 = 0.f, c1 = 0.f, c2 = 0.f;
    #pragma unroll
    for (int k = 0; k < 16; k++){
      float v = sv[k*3 + d];
      c0 += v * sm_wdf[ 0 + k];
      c1 += v * sm_wdf[16 + k];
      c2 += v * sm_wdf[32 + k];
    }
    sm_vdf[ni*9 + d*3 + 0] = c0;
    sm_vdf[ni*9 + d*3 + 1] = c1;
    sm_vdf[ni*9 + d*3 + 2] = c2;
  }
  __syncthreads();

  // ---- phase 2: assemble merged row (scalar | vnorm | sh | pad), stage small tensors
  #pragma unroll
  for (int it = 0; it < 8; it++){
    int idx = tid + it*256;
    int ni = idx >> 5, c4 = (idx & 31) * 4;
    fx4 x = pf[it];
    bfx4 b; b[0]=f2bf(x[0]); b[1]=f2bf(x[1]); b[2]=f2bf(x[2]); b[3]=f2bf(x[3]);
    *(bfx4*)(sm_merged + ni*MS + c4) = b;
  }
  #pragma unroll
  for (int it = 0; it < 4; it++){
    int idx = tid + it*256;
    int ni = idx >> 4, h = idx & 15;
    float x0 = bf2f(sm_vh[ni*48 +  0 + h]);
    float x1 = bf2f(sm_vh[ni*48 + 16 + h]);
    float x2 = bf2f(sm_vh[ni*48 + 32 + h]);
    sm_merged[ni*MS + 128 + h] = f2bf(sqrtf(x0*x0 + x1*x1 + x2*x2 + 1e-8f));
  }
  // sh[c*3+i] = (Fsum[i][:] . vdf[:][c]) / max(cnt,1)   (factorized rotation, per node)
  for (int idx = tid; idx < NPB*9; idx += 256){
    int ni = idx / 9, t = idx - ni*9;
    int c = t / 3, i3 = (t - c*3) * 3;
    float cnt = sm_sh[ni*10 + 9];
    float inv = 1.0f / fmaxf(cnt, 1.0f);
    const float* Fs = sm_sh + ni*10;
    const float* vd = sm_vdf + ni*9;
    float val = Fs[i3+0]*vd[0*3+c] + Fs[i3+1]*vd[1*3+c] + Fs[i3+2]*vd[2*3+c];
    sm_merged[ni*MS + 144 + t] = f2bf(val * inv);
  }
  for (int idx = tid; idx < NPB*7; idx += 256){
    int ni = idx / 7, t = idx - ni*7;
    sm_merged[ni*MS + 153 + t] = 0;            // zero MFMA pad cols 153..159
  }
  for (int idx = tid; idx < 2048; idx += 256)
    sm_wg[(idx >> 7)*WGS + (idx & 127)] = f2bf(wg[idx]);
  {
    float w = wup[tid];
    unsigned short hi = f2bf(w);
    sm_wupb[tid]       = hi;
    sm_wupb[256 + tid] = f2bf(w - bf2f(hi));
  }
  if (tid < 128) sm_bso[tid] = bso[tid];
  if (tid < 16) sm_bg[tid] = bg[tid];
  __syncthreads();

  // ---- phase 3: MFMA scalar_out (B-fragments streamed from prepacked global, L2-resident)
  const int lane = tid & 63;
  const int wv   = tid >> 6;
  const int mrow = lane & 15;
  const int quad = lane >> 4;
  sfx8 afr[5];
  {
    const ushort_t* ab = sm_merged + (wv*16 + mrow)*MS + quad*8;
    #pragma unroll
    for (int ks = 0; ks < 5; ks++) afr[ks] = *(const sfx8*)(ab + ks*32);
  }
  const ushort_t* wb = wpk + lane*8;
  #pragma unroll
  for (int nt = 0; nt < 8; nt++){
    fx4 acc = {0.f, 0.f, 0.f, 0.f};
    #pragma unroll
    for (int ks = 0; ks < 5; ks++){
      sfx8 bfr = *(const sfx8*)(wb + (size_t)(nt*5 + ks)*64*8);
      acc = __builtin_amdgcn_mfma_f32_16x16x32_bf16(afr[ks], bfr, acc, 0, 0, 0);
    }
    const int o = nt*16 + mrow;
    const float bso_v = sm_bso[o];
    #pragma unroll
    for (int r = 0; r < 4; r++){
      int m = quad*4 + r;
      int g = n0 + wv*16 + m;
      float s = acc[r] + bso_v;
      float sact = s / (1.f + __expf(-s));
      if (g < N) out0[(size_t)g*128 + o] = sact;
      sm_merged[(wv*16 + m)*MS + o] = f2bf(sact);
    }
  }
  __syncthreads();

  // ---- phase 4 (MFMA): gate = sigmoid(silu(s) @ Wg^T + bg); vrep[d] = (vh_d @ Wup^T) * gate
  {
    fx4 accg = {0.f, 0.f, 0.f, 0.f};
    const ushort_t* ga = sm_merged + (wv*16 + mrow)*MS + quad*8;
    const ushort_t* gb = sm_wg + mrow*WGS + quad*8;
    #pragma unroll
    for (int ks = 0; ks < 4; ks++){
      sfx8 af = *(const sfx8*)(ga + ks*32);
      sfx8 bf = *(const sfx8*)(gb + ks*32);
      accg = __builtin_amdgcn_mfma_f32_16x16x32_bf16(af, bf, accg, 0, 0, 0);
    }
    float sig[4];
    #pragma unroll
    for (int r = 0; r < 4; r++){
      float gv = accg[r] + sm_bg[mrow];
      sig[r] = 1.f / (1.f + __expf(-gv));
    }
    const sfx8 zero8 = {0,0,0,0,0,0,0,0};
    sfx8 bhi = zero8, blo = zero8;
    if (quad < 2){
      bhi = *(const sfx8*)(sm_wupb + mrow*16 + quad*8);
      blo = *(const sfx8*)(sm_wupb + 256 + mrow*16 + quad*8);
    }
    #pragma unroll
    for (int d = 0; d < 3; d++){
      sfx8 av = zero8;
      if (quad < 2)
        av = *(const sfx8*)(sm_vh + (wv*16 + mrow)*48 + d*16 + quad*8);
      fx4 accv = {0.f, 0.f, 0.f, 0.f};
      accv = __builtin_amdgcn_mfma_f32_16x16x32_bf16(av, blo, accv, 0, 0, 0);
      accv = __builtin_amdgcn_mfma_f32_16x16x32_bf16(av, bhi, accv, 0, 0, 0);
      #pragma unroll
      for (int r = 0; r < 4; r++){
        int m = quad*4 + r;
        int g = n0 + wv*16 + m;
        if (g < N) out1[((size_t)g*16 + mrow)*3 + d] = accv[r] * sig[r];
      }
    }
  }
}

extern "C" void kernel_launch(void* const* d_in, const int* in_sizes, int n_in,
                              void* d_out, int out_size, void* d_ws, size_t ws_size,
                              hipStream_t stream)
{
  const float* scalar = (const float*)d_in[0];
  const float* vec    = (const float*)d_in[1];
  const int*   ei     = (const int*)d_in[2];
  const float* frames = (const float*)d_in[3];
  const float* wdown  = (const float*)d_in[4];
  const float* wdf    = (const float*)d_in[5];
  const float* wso    = (const float*)d_in[6];
  const float* bso    = (const float*)d_in[7];
  const float* wup    = (const float*)d_in[8];
  const float* wg     = (const float*)d_in[9];
  const float* bg     = (const float*)d_in[10];

  const int N = in_sizes[0] / 128;
  const int E = in_sizes[2] / 2;
  const int KB  = (N + 1023) >> 10;                // buckets of 1024 nodes
  const int EPB = (E + NABLK - 1) / NABLK;         // edges per phase-A block

  // per-(bucket,ablock) stream capacity: mean + 3.5 sigma + slack, 16-aligned
  float lam = (float)EPB / (float)KB;
  int capg = (int)(lam + 3.5f * sqrtf(lam) + 17.0f);
  capg = (capg + 15) & ~15;

  char* wp = (char*)d_ws;
  float*        sums  = (float*)wp;                wp += (size_t)N * 10 * sizeof(float);
  ushort_t*     wpk   = (ushort_t*)wp;             wp += (size_t)8*5*64*8 * sizeof(ushort_t);
  int*          counts= (int*)wp;                  wp += (size_t)KB * NABLK * sizeof(int);
  unsigned int* recs  = (unsigned int*)wp;         wp += (size_t)KB * NABLK * capg * RD * sizeof(unsigned int);
  int*          part  = (int*)wp;                  wp += (size_t)KB * SPN * 10240 * sizeof(int);
  const size_t ws_needed = (size_t)(wp - (char*)d_ws);

  float* out0 = (float*)d_out;                     // silu(s): N x 128 f32
  float* out1 = out0 + (size_t)N * 128;            // vrep:    N x 16 x 3 f32

  const bool binned = (ws_size >= ws_needed) && (KB <= KBMAX) && (E < (1 << 25));

  const int N10 = N * 10;
  int prepBlocks = ((N10 + 3) / 4 + 255) / 256;
  if (prepBlocks < 80) prepBlocks = 80;            // ensure >= 20480 threads for wpk pack
  k_prep<<<prepBlocks, 256, 0, stream>>>(wso, wpk, sums, N10);

  if (binned){
    k_part<<<NABLK, RTH, 0, stream>>>(ei, frames, recs, counts, sums, E, EPB, KB, capg);
    k_accum<<<KB * SPN, ATB, 0, stream>>>(recs, counts, part, capg);
    k_node<<<(N + NPB - 1) / NPB, 256, 0, stream>>>(scalar, vec, sums, part,
                                                    wdown, wdf, wpk, bso, wup, wg, bg,
                                                    out0, out1, N);
  } else {
    k_edge<<<(E + 255) / 256, 256, 0, stream>>>(ei, frames, sums, E);
    k_node<<<(N + NPB - 1) / NPB, 256, 0, stream>>>(scalar, vec, sums, nullptr,
                                                    wdown, wdf, wpk, bso, wup, wg, bg,
                                                    out0, out1, N);
  }
}

// Round 15
// 206.519 us; speedup vs baseline: 1.0761x; 1.0288x over previous
//
#include <hip/hip_runtime.h>

typedef unsigned short ushort_t;
typedef __attribute__((ext_vector_type(4))) unsigned short bfx4;
typedef __attribute__((ext_vector_type(8))) unsigned short bfx8;
typedef __attribute__((ext_vector_type(8))) short sfx8;
typedef __attribute__((ext_vector_type(4))) float fx4;

#define NABLK  512     // phase-A blocks (512 x 2/CU -> all 256 CUs busy)
#define RTH    1024    // phase-A threads per block
#define KBMAX  52      // max buckets (node>>10); N <= 53248 else fallback
#define CAPL   60      // LDS records per bucket: 52*60*6*4=74880B -> total ~77.3KB -> 2 blocks/CU
#define FLC    16      // flush chunk, records
#define RD     6       // record dwords (24 B): 4x f16x2 + (f16|loc<<16) + pad
#define QMAX   224     // flush queue capacity per round (<= KBMAX*4)
#define SPN    8       // phase-B sub-blocks per bucket (part table = KB*8*40KB = 16MB)
#define ATB    512     // phase-B threads per block

#define FXS 4194304.0f           // 2^22 fixed-point scale (range ±512, lsb 2.4e-7)
#define FXONE (1 << 22)

__device__ __forceinline__ float bf2f(unsigned short u){
  unsigned int x = ((unsigned int)u) << 16;
  float f; __builtin_memcpy(&f, &x, 4); return f;
}
__device__ __forceinline__ unsigned short f2bf(float f){
  unsigned int x; __builtin_memcpy(&x, &f, 4);
  x += 0x7fffu + ((x >> 16) & 1u);
  return (unsigned short)(x >> 16);
}
__device__ __forceinline__ int f2fx(float v){ return __float2int_rn(v * FXS); }
__device__ __forceinline__ unsigned short f2h(float f){
  _Float16 h = (_Float16)f;
  unsigned short u; __builtin_memcpy(&u, &h, 2); return u;
}
__device__ __forceinline__ float h2f(unsigned int u16){
  unsigned short us = (unsigned short)u16;
  _Float16 h; __builtin_memcpy(&h, &us, 2); return (float)h;
}
__device__ __forceinline__ unsigned int pk2(float a, float b){
  return (unsigned int)f2h(a) | ((unsigned int)f2h(b) << 16);
}

// ---------------- prep: zero sums (fx4 stores) + pack W_so into bf16 MFMA-B-fragment order.
__global__ __launch_bounds__(256) void k_prep(const float* __restrict__ wso,
                                              ushort_t* __restrict__ wpk,
                                              float* __restrict__ sums, int N10)
{
  int gid = blockIdx.x * 256 + threadIdx.x;
  int b4 = gid * 4;
  if (b4 + 4 <= N10){
    fx4 z = {0.f, 0.f, 0.f, 0.f};
    *(fx4*)(sums + b4) = z;
  } else if (b4 < N10){
    for (int t = b4; t < N10; t++) sums[t] = 0.f;
  }
  if (gid < 8*5*64*8){
    int j    = gid & 7;
    int lane = (gid >> 3) & 63;
    int ks   = (gid >> 9) % 5;
    int nt   = gid / 2560;
    int mrow = lane & 15, quad = lane >> 4;
    int o = nt*16 + mrow;
    int k = ks*32 + quad*8 + j;
    float v = (k < 153) ? wso[o*153 + k] : 0.f;
    wpk[gid] = f2bf(v);
  }
}

// ---------------- pure-atomic fallback (ws too small / N too large)
__global__ void k_edge(const int* __restrict__ ei, const float* __restrict__ frames,
                       float* __restrict__ sums, int E)
{
  int e = blockIdx.x * 256 + threadIdx.x;
  if (e >= E) return;
  int row = ei[e];
  const float* fp = frames + (size_t)e * 9;
  float F[9];
  __builtin_memcpy(F, fp, 36);
  float* sp = sums + (size_t)row * 10;
  #pragma unroll
  for (int t = 0; t < 9; t++) atomicAdd(&sp[t], F[t]);
  atomicAdd(&sp[9], 1.0f);
}

// ---------------- Phase A: LDS-staged radix partition into per-(bucket,block) record streams.
// Records are 24B f16-packed (loc + 9 frame values). All stream writes full-line coalesced.
__global__ __launch_bounds__(RTH) void k_part(const int* __restrict__ ei,
                                              const float* __restrict__ frames,
                                              unsigned int* __restrict__ recs,
                                              int* __restrict__ counts,
                                              float* __restrict__ sums,
                                              int E, int EPB, int KB, int CAPG)
{
  __shared__ unsigned int s_buf[KBMAX * CAPL * RD];   // 74880B; total ~77.3KB -> 2 blocks/CU
  __shared__ int s_cnt[KBMAX];
  __shared__ int s_gof[KBMAX];
  __shared__ int s_cap[KBMAX];                        // first-fallback doff (stream cap actually stored)
  __shared__ int s_qb[QMAX];                          // (bucket<<8) | srcStartSlot
  __shared__ int s_qd[QMAX];                          // dst record offset, or -1 = fallback
  __shared__ int s_nq;

  const int tid  = threadIdx.x;
  const int ablk = blockIdx.x;
  const int e0 = ablk * EPB;
  const int e1 = min(e0 + EPB, E);

  for (int b = tid; b < KB; b += RTH){ s_cnt[b] = 0; s_gof[b] = 0; s_cap[b] = CAPG; }
  if (tid == 0) s_nq = 0;
  __syncthreads();

  for (int i0 = e0; i0 < e1; i0 += RTH){
    // ---- classify (coalesced reads of ei + frames), pack record into LDS
    int e = i0 + tid;
    if (e < e1){
      int row = ei[e];
      float F[9];
      __builtin_memcpy(F, frames + (size_t)e * 9, 36);
      int b   = row >> 10;
      int loc = row & 1023;
      int slot = atomicAdd(&s_cnt[b], 1);     // ds_add_rtn_u32 (native int)
      if (slot < CAPL){
        uint2* d2 = (uint2*)(s_buf + (b * CAPL + slot) * RD);
        d2[0] = make_uint2(pk2(F[0], F[1]), pk2(F[2], F[3]));
        d2[1] = make_uint2(pk2(F[4], F[5]), pk2(F[6], F[7]));
        d2[2] = make_uint2((unsigned int)f2h(F[8]) | ((unsigned int)loc << 16), 0u);
      } else {
        // LDS buffer overflow (rare): fabric atomics, correctness-preserving
        float* sp = sums + (size_t)row * 10;
        #pragma unroll
        for (int t = 0; t < 9; t++) atomicAdd(&sp[t], F[t]);
        atomicAdd(&sp[9], 1.0f);
      }
    }
    __syncthreads();
    // ---- flush detect: one thread per bucket queues full 16-record chunks (from the top)
    if (tid < KB){
      int c = min(s_cnt[tid], CAPL);
      int nf = c >> 4;
      int rem = c & (FLC - 1);
      if (nf > 0){
        int off = s_gof[tid];
        s_gof[tid] = off + nf * FLC;
        for (int k = 0; k < nf; k++){
          int q = atomicAdd(&s_nq, 1);
          int doff = off + k * FLC;
          s_qb[q] = (tid << 8) | (rem + k * FLC);
          if (doff + FLC <= CAPG){
            s_qd[q] = doff;
          } else {
            s_qd[q] = -1;
            s_cap[tid] = min(s_cap[tid], doff);   // doff monotone -> fallbacks are a suffix
          }
        }
        s_cnt[tid] = rem;
      }
    }
    __syncthreads();
    // ---- cooperative copy: 96 dwords per chunk (384B), fully coalesced
    const int nq = s_nq;
    for (int i = tid; i < nq * (FLC * RD); i += RTH){
      int q = i / (FLC * RD), d = i - q * (FLC * RD);
      int doff = s_qd[q];
      if (doff >= 0){
        int bb = s_qb[q] >> 8, ss = s_qb[q] & 255;
        recs[((size_t)(bb * NABLK + ablk) * CAPG + doff) * RD + d] =
            s_buf[(bb * CAPL + ss) * RD + d];
      }
    }
    // ---- fallback pass for capacity-overflowed chunks (rare): per-record fabric atomics
    for (int i = tid; i < nq * FLC; i += RTH){
      int q = i / FLC, rr = i - q * FLC;
      if (s_qd[q] < 0){
        int bb = s_qb[q] >> 8, ss = (s_qb[q] & 255) + rr;
        const unsigned int* rp = s_buf + (bb * CAPL + ss) * RD;
        int loc = rp[4] >> 16;
        float* sp = sums + (size_t)((bb << 10) + loc) * 10;
        atomicAdd(&sp[0], h2f(rp[0] & 65535u)); atomicAdd(&sp[1], h2f(rp[0] >> 16));
        atomicAdd(&sp[2], h2f(rp[1] & 65535u)); atomicAdd(&sp[3], h2f(rp[1] >> 16));
        atomicAdd(&sp[4], h2f(rp[2] & 65535u)); atomicAdd(&sp[5], h2f(rp[2] >> 16));
        atomicAdd(&sp[6], h2f(rp[3] & 65535u)); atomicAdd(&sp[7], h2f(rp[3] >> 16));
        atomicAdd(&sp[8], h2f(rp[4] & 65535u)); atomicAdd(&sp[9], 1.0f);
      }
    }
    __syncthreads();
    if (tid == 0) s_nq = 0;   // next read is after the classify barrier
  }

  // ---- drain leftovers (<16 per bucket) + write counts
  for (int i = tid; i < KB * FLC; i += RTH){
    int b = i / FLC, rec = i - b * FLC;
    if (rec < s_cnt[b]){
      int off = s_gof[b] + rec;
      const unsigned int* rp = s_buf + (b * CAPL + rec) * RD;
      if (off < s_cap[b]){
        uint2* dp = (uint2*)(recs + ((size_t)(b * NABLK + ablk) * CAPG + off) * RD);
        dp[0] = make_uint2(rp[0], rp[1]);
        dp[1] = make_uint2(rp[2], rp[3]);
        dp[2] = make_uint2(rp[4], rp[5]);
      } else {
        int loc = rp[4] >> 16;
        float* sp = sums + (size_t)((b << 10) + loc) * 10;
        atomicAdd(&sp[0], h2f(rp[0] & 65535u)); atomicAdd(&sp[1], h2f(rp[0] >> 16));
        atomicAdd(&sp[2], h2f(rp[1] & 65535u)); atomicAdd(&sp[3], h2f(rp[1] >> 16));
        atomicAdd(&sp[4], h2f(rp[2] & 65535u)); atomicAdd(&sp[5], h2f(rp[2] >> 16));
        atomicAdd(&sp[6], h2f(rp[3] & 65535u)); atomicAdd(&sp[7], h2f(rp[3] >> 16));
        atomicAdd(&sp[8], h2f(rp[4] & 65535u)); atomicAdd(&sp[9], 1.0f);
      }
    }
  }
  if (tid < KB)
    counts[tid * NABLK + ablk] = min(s_gof[tid] + s_cnt[tid], s_cap[tid]);
}

// ---------------- Phase B: per (bucket, sp) sub-block, sequential record reads.
// Fixed-point int accumulate via native ds_add_u32; partial tables stay INT (exact, no cvt).
// 512 threads x (KB*8) blocks: same thread-parallelism as 256x(KB*16), half the part traffic.
__global__ __launch_bounds__(ATB) void k_accum(const unsigned int* __restrict__ recs,
                                               const int* __restrict__ counts,
                                               int* __restrict__ part, int CAPG)
{
  constexpr int APS2 = NABLK / SPN;     // 64
  __shared__ int s_pref[APS2 + 1];
  __shared__ int s_acc[1024 * 11];      // fixed-point Q22; stride 11: gcd(11,32)=1
  const int bucket = blockIdx.x / SPN;
  const int sp     = blockIdx.x - bucket * SPN;
  const int tid    = threadIdx.x;

  if (tid < APS2) s_pref[tid + 1] = counts[bucket * NABLK + sp * APS2 + tid];
  if (tid == 0) s_pref[0] = 0;
  for (int i = tid; i < 1024 * 11; i += ATB) s_acc[i] = 0;
  __syncthreads();
  #pragma unroll
  for (int off = 1; off < APS2; off <<= 1){
    int v = 0;
    if (tid < APS2 && tid + 1 > off) v = s_pref[tid + 1 - off];
    __syncthreads();
    if (tid < APS2) s_pref[tid + 1] += v;
    __syncthreads();
  }
  const int total = s_pref[APS2];

  for (int base = 0; base < total; base += ATB * 4){
    int got[4]; size_t ra[4];
    #pragma unroll
    for (int u = 0; u < 4; u++){
      got[u] = 0; ra[u] = 0;
      int idx = base + u * ATB + tid;
      if (idx < total){
        int lo = 0, hi = APS2;
        while (hi - lo > 1){ int mid = (lo + hi) >> 1; if (s_pref[mid] <= idx) lo = mid; else hi = mid; }
        int slot = idx - s_pref[lo];
        int ablk = sp * APS2 + lo;
        ra[u] = ((size_t)(bucket * NABLK + ablk) * CAPG + slot);
        got[u] = 1;
      }
    }
    uint2 a0[4], a1[4], a2[4];
    #pragma unroll
    for (int u = 0; u < 4; u++){
      if (got[u]){
        const unsigned int* rp = recs + ra[u] * RD;   // 24B-aligned sequential
        a0[u] = *(const uint2*)(rp + 0);
        a1[u] = *(const uint2*)(rp + 2);
        a2[u] = *(const uint2*)(rp + 4);
      }
    }
    #pragma unroll
    for (int u = 0; u < 4; u++){
      if (got[u]){
        int loc = a2[u].x >> 16;
        int* ap = s_acc + loc * 11;
        atomicAdd(&ap[0], f2fx(h2f(a0[u].x & 65535u)));   // ds_add_u32: native
        atomicAdd(&ap[1], f2fx(h2f(a0[u].x >> 16)));
        atomicAdd(&ap[2], f2fx(h2f(a0[u].y & 65535u)));
        atomicAdd(&ap[3], f2fx(h2f(a0[u].y >> 16)));
        atomicAdd(&ap[4], f2fx(h2f(a1[u].x & 65535u)));
        atomicAdd(&ap[5], f2fx(h2f(a1[u].x >> 16)));
        atomicAdd(&ap[6], f2fx(h2f(a1[u].y & 65535u)));
        atomicAdd(&ap[7], f2fx(h2f(a1[u].y >> 16)));
        atomicAdd(&ap[8], f2fx(h2f(a2[u].x & 65535u)));
        atomicAdd(&ap[9], FXONE);
      }
    }
  }
  __syncthreads();
  int* pb = part + (size_t)(bucket * SPN + sp) * 10240;
  for (int i = tid; i < 10240; i += ATB)
    pb[i] = s_acc[(i / 10) * 11 + (i % 10)];
}

// ---------------- Kernel C: node main pass (vh, vdf, vnorm, Fsum->sh, MFMA s, MFMA gate/vrep)
#define NPB 64
#define MS  168   // padded row stride (elements); 168*2B/4 = 84 ≡ 20 mod 32 -> <=2-way LDS conflicts
#define WGS 136   // sm_wg row stride (shorts): 272B, 16B-aligned, 68 dw ≡ 4 mod 32 -> <=2-way

__global__ __launch_bounds__(256) void k_node(
    const float* __restrict__ scalar, const float* __restrict__ vec,
    const float* __restrict__ sums,   const int* __restrict__ part,
    const float* __restrict__ wdown, const float* __restrict__ wdf,
    const ushort_t* __restrict__ wpk, const float* __restrict__ bso,
    const float* __restrict__ wup,   const float* __restrict__ wg,
    const float* __restrict__ bg,
    float* __restrict__ out0, float* __restrict__ out1, int N)
{
  __shared__ __align__(16) ushort_t sm_merged[NPB * MS];  // phases 0-1: first 12288B hold vec f32
  __shared__ __align__(16) ushort_t sm_vh[NPB * 48];
  __shared__ __align__(16) ushort_t sm_wg[16 * WGS];
  __shared__ __align__(16) ushort_t sm_wupb[512];  // [0:256) bf16 hi, [256:512) bf16 lo residual
  __shared__ float  sm_sh[NPB * 10];     // Fsum[9] + cnt per node
  __shared__ float  sm_vdf[NPB * 9];     // vdf[d*3+c] per node
  __shared__ float  sm_wd[256];          // transposed: sm_wd[k*16+h] = wdown[h*16+k]
  __shared__ float  sm_wdf[48];
  __shared__ float  sm_bso[128];
  __shared__ float  sm_bg[16];

  const int tid = threadIdx.x;
  const int n0  = blockIdx.x * NPB;

  // ---- T14 issue-early: scalar loads issued NOW, consumed in phase 2.
  fx4 pf[8];
  #pragma unroll
  for (int it = 0; it < 8; it++){
    int idx = tid + it*256;
    int ni = idx >> 5, c4 = (idx & 31) * 4;
    int g = n0 + ni;
    fx4 z = {0.f, 0.f, 0.f, 0.f};
    pf[it] = (g < N) ? *(const fx4*)(scalar + (size_t)g*128 + c4) : z;
  }

  // ---- phase 0: stage vec (as f32 into sm_merged), wd/wdf, reduce partial Fsum tables (int, exact)
  {
    int nv = N - n0; if (nv > NPB) nv = NPB;
    const int valid = nv * 48;
    fx4* scratch = (fx4*)sm_merged;
    for (int idx = tid; idx < NPB*48/4; idx += 256){
      fx4 val = {0.f, 0.f, 0.f, 0.f};
      if (idx*4 < valid) val = *(const fx4*)(vec + (size_t)n0*48 + idx*4);
      scratch[idx] = val;
    }
  }
  sm_wd[tid] = wdown[(tid & 15)*16 + (tid >> 4)];   // transpose on load
  if (tid < 48) sm_wdf[tid] = wdf[tid];
  for (int idx = tid; idx < NPB*10; idx += 256){
    int ni = idx / 10, sl = idx - ni*10;
    int g = n0 + ni;
    float acc = 0.f;
    if (g < N){
      acc = sums[(size_t)g*10 + sl];           // rare overflow-fallback adds (usually 0)
      if (part){
        int bucket = g >> 10, loc = g & 1023;
        const int* pb = part + (size_t)bucket * SPN * 10240 + loc * 10 + sl;
        int ai = 0;
        #pragma unroll
        for (int sp = 0; sp < SPN; sp++) ai += pb[(size_t)sp * 10240];
        acc += (float)ai * (1.0f / FXS);
      }
    }
    sm_sh[idx] = acc;
  }
  __syncthreads();

  // ---- phase 1: vh (1024 items (ni,h), weight reads broadcast) + vdf (192 items)
  #pragma unroll
  for (int it = 0; it < 4; it++){
    int idx = tid + it*256;
    int ni = idx >> 4, h = idx & 15;
    const float* sv = (const float*)sm_merged + ni*48;
    float a0 = 0.f, a1 = 0.f, a2 = 0.f;
    #pragma unroll
    for (int k = 0; k < 16; k++){
      float w = sm_wd[k*16 + h];
      a0 += sv[k*3+0]*w; a1 += sv[k*3+1]*w; a2 += sv[k*3+2]*w;
    }
    sm_vh[ni*48 +  0 + h] = f2bf(a0);
    sm_vh[ni*48 + 16 + h] = f2bf(a1);
    sm_vh[ni*48 + 32 + h] = f2bf(a2);
  }
  if (tid < NPB*3){
    const int ni = tid / 3, d = tid - ni*3;
    const float* sv = (const float*)sm_merged + ni*48;
    float c0 = 0.f, c1 = 0.f, c2 = 0.f;
    #pragma unroll
    for (int k = 0; k < 16; k++){
      float v = sv[k*3 + d];
      c0 += v * sm_wdf[ 0 + k];
      c1 += v * sm_wdf[16 + k];
      c2 += v * sm_wdf[32 + k];
    }
    sm_vdf[ni*9 + d*3 + 0] = c0;
    sm_vdf[ni*9 + d*3 + 1] = c1;
    sm_vdf[ni*9 + d*3 + 2] = c2;
  }
  __syncthreads();

  // ---- phase 2: assemble merged row (scalar | vnorm | sh | pad), stage small tensors
  #pragma unroll
  for (int it = 0; it < 8; it++){
    int idx = tid + it*256;
    int ni = idx >> 5, c4 = (idx & 31) * 4;
    fx4 x = pf[it];
    bfx4 b; b[0]=f2bf(x[0]); b[1]=f2bf(x[1]); b[2]=f2bf(x[2]); b[3]=f2bf(x[3]);
    *(bfx4*)(sm_merged + ni*MS + c4) = b;
  }
  #pragma unroll
  for (int it = 0; it < 4; it++){
    int idx = tid + it*256;
    int ni = idx >> 4, h = idx & 15;
    float x0 = bf2f(sm_vh[ni*48 +  0 + h]);
    float x1 = bf2f(sm_vh[ni*48 + 16 + h]);
    float x2 = bf2f(sm_vh[ni*48 + 32 + h]);
    sm_merged[ni*MS + 128 + h] = f2bf(sqrtf(x0*x0 + x1*x1 + x2*x2 + 1e-8f));
  }
  // sh[c*3+i] = (Fsum[i][:] . vdf[:][c]) / max(cnt,1)   (factorized rotation, per node)
  for (int idx = tid; idx < NPB*9; idx += 256){
    int ni = idx / 9, t = idx - ni*9;
    int c = t / 3, i3 = (t - c*3) * 3;
    float cnt = sm_sh[ni*10 + 9];
    float inv = 1.0f / fmaxf(cnt, 1.0f);
    const float* Fs = sm_sh + ni*10;
    const float* vd = sm_vdf + ni*9;
    float val = Fs[i3+0]*vd[0*3+c] + Fs[i3+1]*vd[1*3+c] + Fs[i3+2]*vd[2*3+c];
    sm_merged[ni*MS + 144 + t] = f2bf(val * inv);
  }
  for (int idx = tid; idx < NPB*7; idx += 256){
    int ni = idx / 7, t = idx - ni*7;
    sm_merged[ni*MS + 153 + t] = 0;            // zero MFMA pad cols 153..159
  }
  for (int idx = tid; idx < 2048; idx += 256)
    sm_wg[(idx >> 7)*WGS + (idx & 127)] = f2bf(wg[idx]);
  {
    float w = wup[tid];
    unsigned short hi = f2bf(w);
    sm_wupb[tid]       = hi;
    sm_wupb[256 + tid] = f2bf(w - bf2f(hi));
  }
  if (tid < 128) sm_bso[tid] = bso[tid];
  if (tid < 16) sm_bg[tid] = bg[tid];
  __syncthreads();

  // ---- phase 3: MFMA scalar_out (B-fragments streamed from prepacked global, L2-resident)
  const int lane = tid & 63;
  const int wv   = tid >> 6;
  const int mrow = lane & 15;
  const int quad = lane >> 4;
  sfx8 afr[5];
  {
    const ushort_t* ab = sm_merged + (wv*16 + mrow)*MS + quad*8;
    #pragma unroll
    for (int ks = 0; ks < 5; ks++) afr[ks] = *(const sfx8*)(ab + ks*32);
  }
  const ushort_t* wb = wpk + lane*8;
  #pragma unroll
  for (int nt = 0; nt < 8; nt++){
    fx4 acc = {0.f, 0.f, 0.f, 0.f};
    #pragma unroll
    for (int ks = 0; ks < 5; ks++){
      sfx8 bfr = *(const sfx8*)(wb + (size_t)(nt*5 + ks)*64*8);
      acc = __builtin_amdgcn_mfma_f32_16x16x32_bf16(afr[ks], bfr, acc, 0, 0, 0);
    }
    const int o = nt*16 + mrow;
    const float bso_v = sm_bso[o];
    #pragma unroll
    for (int r = 0; r < 4; r++){
      int m = quad*4 + r;
      int g = n0 + wv*16 + m;
      float s = acc[r] + bso_v;
      float sact = s / (1.f + __expf(-s));
      if (g < N) out0[(size_t)g*128 + o] = sact;
      sm_merged[(wv*16 + m)*MS + o] = f2bf(sact);
    }
  }
  __syncthreads();

  // ---- phase 4 (MFMA): gate = sigmoid(silu(s) @ Wg^T + bg); vrep[d] = (vh_d @ Wup^T) * gate
  {
    fx4 accg = {0.f, 0.f, 0.f, 0.f};
    const ushort_t* ga = sm_merged + (wv*16 + mrow)*MS + quad*8;
    const ushort_t* gb = sm_wg + mrow*WGS + quad*8;
    #pragma unroll
    for (int ks = 0; ks < 4; ks++){
      sfx8 af = *(const sfx8*)(ga + ks*32);
      sfx8 bf = *(const sfx8*)(gb + ks*32);
      accg = __builtin_amdgcn_mfma_f32_16x16x32_bf16(af, bf, accg, 0, 0, 0);
    }
    float sig[4];
    #pragma unroll
    for (int r = 0; r < 4; r++){
      float gv = accg[r] + sm_bg[mrow];
      sig[r] = 1.f / (1.f + __expf(-gv));
    }
    const sfx8 zero8 = {0,0,0,0,0,0,0,0};
    sfx8 bhi = zero8, blo = zero8;
    if (quad < 2){
      bhi = *(const sfx8*)(sm_wupb + mrow*16 + quad*8);
      blo = *(const sfx8*)(sm_wupb + 256 + mrow*16 + quad*8);
    }
    #pragma unroll
    for (int d = 0; d < 3; d++){
      sfx8 av = zero8;
      if (quad < 2)
        av = *(const sfx8*)(sm_vh + (wv*16 + mrow)*48 + d*16 + quad*8);
      fx4 accv = {0.f, 0.f, 0.f, 0.f};
      accv = __builtin_amdgcn_mfma_f32_16x16x32_bf16(av, blo, accv, 0, 0, 0);
      accv = __builtin_amdgcn_mfma_f32_16x16x32_bf16(av, bhi, accv, 0, 0, 0);
      #pragma unroll
      for (int r = 0; r < 4; r++){
        int m = quad*4 + r;
        int g = n0 + wv*16 + m;
        if (g < N) out1[((size_t)g*16 + mrow)*3 + d] = accv[r] * sig[r];
      }
    }
  }
}

extern "C" void kernel_launch(void* const* d_in, const int* in_sizes, int n_in,
                              void* d_out, int out_size, void* d_ws, size_t ws_size,
                              hipStream_t stream)
{
  const float* scalar = (const float*)d_in[0];
  const float* vec    = (const float*)d_in[1];
  const int*   ei     = (const int*)d_in[2];
  const float* frames = (const float*)d_in[3];
  const float* wdown  = (const float*)d_in[4];
  const float* wdf    = (const float*)d_in[5];
  const float* wso    = (const float*)d_in[6];
  const float* bso    = (const float*)d_in[7];
  const float* wup    = (const float*)d_in[8];
  const float* wg     = (const float*)d_in[9];
  const float* bg     = (const float*)d_in[10];

  const int N = in_sizes[0] / 128;
  const int E = in_sizes[2] / 2;
  const int KB  = (N + 1023) >> 10;                // buckets of 1024 nodes
  const int EPB = (E + NABLK - 1) / NABLK;         // edges per phase-A block

  // per-(bucket,ablock) stream capacity: mean + 3.5 sigma + slack, 16-aligned
  float lam = (float)EPB / (float)KB;
  int capg = (int)(lam + 3.5f * sqrtf(lam) + 17.0f);
  capg = (capg + 15) & ~15;

  char* wp = (char*)d_ws;
  float*        sums  = (float*)wp;                wp += (size_t)N * 10 * sizeof(float);
  ushort_t*     wpk   = (ushort_t*)wp;             wp += (size_t)8*5*64*8 * sizeof(ushort_t);
  int*          counts= (int*)wp;                  wp += (size_t)KB * NABLK * sizeof(int);
  unsigned int* recs  = (unsigned int*)wp;         wp += (size_t)KB * NABLK * capg * RD * sizeof(unsigned int);
  int*          part  = (int*)wp;                  wp += (size_t)KB * SPN * 10240 * sizeof(int);
  const size_t ws_needed = (size_t)(wp - (char*)d_ws);

  float* out0 = (float*)d_out;                     // silu(s): N x 128 f32
  float* out1 = out0 + (size_t)N * 128;            // vrep:    N x 16 x 3 f32

  const bool binned = (ws_size >= ws_needed) && (KB <= KBMAX) && (E < (1 << 25));

  const int N10 = N * 10;
  int prepBlocks = ((N10 + 3) / 4 + 255) / 256;
  if (prepBlocks < 80) prepBlocks = 80;            // ensure >= 20480 threads for wpk pack
  k_prep<<<prepBlocks, 256, 0, stream>>>(wso, wpk, sums, N10);

  if (binned){
    k_part<<<NABLK, RTH, 0, stream>>>(ei, frames, recs, counts, sums, E, EPB, KB, capg);
    k_accum<<<KB * SPN, ATB, 0, stream>>>(recs, counts, part, capg);
    k_node<<<(N + NPB - 1) / NPB, 256, 0, stream>>>(scalar, vec, sums, part,
                                                    wdown, wdf, wpk, bso, wup, wg, bg,
                                                    out0, out1, N);
  } else {
    k_edge<<<(E + 255) / 256, 256, 0, stream>>>(ei, frames, sums, E);
    k_node<<<(N + NPB - 1) / NPB, 256, 0, stream>>>(scalar, vec, sums, nullptr,
                                                    wdown, wdf, wpk, bso, wup, wg, bg,
                                                    out0, out1, N);
  }
}